// Round 4
// baseline (2396.804 us; speedup 1.0000x reference)
//
#include <hip/hip_runtime.h>
#include <math.h>

#define BB 8
#define SS 2048
#define DD 512
#define LL 6
#define FFD 2048   // 4*D

typedef _Float16 half_t;
typedef __attribute__((ext_vector_type(8))) _Float16 half8;
typedef __attribute__((ext_vector_type(4))) _Float16 half4;
typedef __attribute__((ext_vector_type(4))) float f32x4;

enum { EPI_NONE = 0, EPI_RELU = 2, EPI_RES = 3, EPI_ATTN = 4, EPI_QKV = 5 };

// ---------------- async global->LDS, 16B per lane ----------------
__device__ __forceinline__ void gl_lds16(const void* g, void* l) {
    __builtin_amdgcn_global_load_lds(
        (const __attribute__((address_space(1))) unsigned int*)g,
        (__attribute__((address_space(3))) unsigned int*)l,
        16, 0, 0);
}

__device__ __forceinline__ void blockReduce2(float& a, float& b, float* sm) {
#pragma unroll
    for (int off = 32; off; off >>= 1) {
        a += __shfl_down(a, off);
        b += __shfl_down(b, off);
    }
    int lane = threadIdx.x & 63;
    int w = threadIdx.x >> 6;
    if (lane == 0) { sm[w] = a; sm[4 + w] = b; }
    __syncthreads();
    a = sm[0] + sm[1] + sm[2] + sm[3];
    b = sm[4] + sm[5] + sm[6] + sm[7];
    __syncthreads();
}

// ---------------- encoder ----------------
__global__ __launch_bounds__(256) void encode_kernel(
    const float* __restrict__ z, const float* __restrict__ c,
    const float* __restrict__ enc_w, const float* __restrict__ enc_b,
    float* __restrict__ x)
{
    int idx = blockIdx.x * 256 + threadIdx.x;
    int d  = idx & (DD - 1);
    int bs = idx >> 9;
    int s  = bs & (SS - 1);
    float v = z[bs] * enc_w[2 * d] + c[bs] * enc_w[2 * d + 1] + enc_b[d];
    float div = expf(-(float)(d & ~1) * (9.210340371976184f / 512.0f));
    float ang = (float)s * div;
    v += (d & 1) ? cosf(ang) : sinf(ang);
    x[idx] = v;
}

// ------- per-layer weight conversion, one dispatch: [wq|wk|wv] + ff1 + ff2 -------
__global__ __launch_bounds__(256) void convert_layer_kernel(
    const float* __restrict__ wq, const float* __restrict__ wk,
    const float* __restrict__ wv, const float* __restrict__ f1,
    const float* __restrict__ f2, half_t* __restrict__ wqkv,
    half_t* __restrict__ f1h, half_t* __restrict__ f2h)
{
    const int NQ = DD * DD;                      // 262144
    int i = blockIdx.x * 256 + threadIdx.x;      // 0 .. 3*NQ + 2*FFD*DD
    if (i < 3 * NQ) {
        int which = i >> 18, j = i & (NQ - 1);
        const float* s = (which == 0) ? wq : (which == 1) ? wk : wv;
        wqkv[i] = (half_t)s[j];
    } else {
        int k = i - 3 * NQ;
        if (k < FFD * DD) f1h[k] = (half_t)f1[k];
        else              f2h[k - FFD * DD] = (half_t)f2[k - FFD * DD];
    }
}

// ---------------- attention bias tables: tbl[l][dist] ----------------
__global__ __launch_bounds__(256) void bias_table_kernel(
    const float* __restrict__ beta, float* __restrict__ tbl)
{
    int i = blockIdx.x * 256 + threadIdx.x;   // L*2048
    int l = i >> 11, d = i & (SS - 1);
    tbl[i] = beta[2 * l] * cosf(0.2617993877991494f * d)
           + beta[2 * l + 1] * cosf(0.008726646259971648f * d);
}

// ---------------- LN: dst(half) = LN(src)*w + b ----------------
__global__ __launch_bounds__(256) void ln_kernel(
    const float* __restrict__ src, const float* __restrict__ w,
    const float* __restrict__ b, half_t* __restrict__ dst)
{
    __shared__ float sm[8];
    size_t row = blockIdx.x;
    const float* p = src + row * DD;
    int t = threadIdx.x;
    float v0 = p[t], v1 = p[t + 256];
    float s = v0 + v1, sq = v0 * v0 + v1 * v1;
    blockReduce2(s, sq, sm);
    float mean = s * (1.0f / DD);
    float var  = sq * (1.0f / DD) - mean * mean;
    float rs   = rsqrtf(var + 1e-5f);
    dst[row * DD + t]       = (half_t)((v0 - mean) * rs * w[t] + b[t]);
    dst[row * DD + t + 256] = (half_t)((v1 - mean) * rs * w[t + 256] + b[t + 256]);
}

// -------- fused: x = LN(x + att, w1,b1); xn(half) = LN(x, w2,b2) --------
__global__ __launch_bounds__(256) void add_ln_ln_kernel(
    float* __restrict__ x, const half_t* __restrict__ att,
    const float* __restrict__ w1, const float* __restrict__ b1,
    const float* __restrict__ w2, const float* __restrict__ b2,
    half_t* __restrict__ xn)
{
    __shared__ float sm[8];
    size_t row = blockIdx.x;
    int t = threadIdx.x;
    float v0 = x[row * DD + t] + (float)att[row * DD + t];
    float v1 = x[row * DD + t + 256] + (float)att[row * DD + t + 256];
    float s = v0 + v1, sq = v0 * v0 + v1 * v1;
    blockReduce2(s, sq, sm);
    float mean = s * (1.0f / DD);
    float var  = sq * (1.0f / DD) - mean * mean;
    float rs   = rsqrtf(var + 1e-5f);
    float y0 = (v0 - mean) * rs * w1[t] + b1[t];
    float y1 = (v1 - mean) * rs * w1[t + 256] + b1[t + 256];
    x[row * DD + t]       = y0;
    x[row * DD + t + 256] = y1;
    s = y0 + y1; sq = y0 * y0 + y1 * y1;
    blockReduce2(s, sq, sm);
    mean = s * (1.0f / DD);
    var  = sq * (1.0f / DD) - mean * mean;
    rs   = rsqrtf(var + 1e-5f);
    xn[row * DD + t]       = (half_t)((y0 - mean) * rs * w2[t] + b2[t]);
    xn[row * DD + t + 256] = (half_t)((y1 - mean) * rs * w2[t + 256] + b2[t + 256]);
}

// ---------------- MFMA fp16 NT GEMM ----------------
// C[m,n] = sum_k A[m,k]*W[n,k]. Tile MT x 128, BK=32, 256 thr = 4 waves.
// Orientation: EPI_QKV uses mfma(a,b) (m in regs -> packed V^T store).
// All others use SWAPPED mfma(b,a): m on lanes, n in regs -> packed
// half4/float4 row-major stores (16 stores/thread instead of 64 scattered).
template<int MT, int EPI, bool OHALF>
__global__ __launch_bounds__(256) void gemm_mfma(
    const half_t* __restrict__ A, const half_t* __restrict__ W,
    const float* __restrict__ bias, const float* __restrict__ res,
    void* __restrict__ Cp, int N, int K, float alpha,
    long long sA, long long sW, long long sC,
    const float* __restrict__ biasK, const float* __restrict__ biasV,
    half_t* __restrict__ Ck, half_t* __restrict__ Cv)
{
    constexpr int TM = MT / 32;                  // mfma m-tiles per wave
    constexpr bool SW = (EPI != EPI_QKV);        // swapped orientation
    __shared__ __align__(16) half_t As[MT * 32];
    __shared__ __align__(16) half_t Bs[128 * 32];

    const int z = blockIdx.z;
    A += (size_t)z * sA; W += (size_t)z * sW;
    float*  Cf = (float*)Cp  + (size_t)z * sC;
    half_t* Ch = (half_t*)Cp + (size_t)z * sC;

    const int tid = threadIdx.x;
    const int wv = tid >> 6, ln = tid & 63;
    const int bm = blockIdx.x * MT, bn = blockIdx.y * 128;
    const int wm = (wv & 1) * (MT / 2), wn = (wv >> 1) * 64;

    const int srow = wv * 16 + (ln >> 2);        // 0..63
    const int scol = (ln & 3) * 8;
    const half_t* Ag = A + (size_t)(bm + srow) * K + scol;
    const half_t* Bg = W + (size_t)(bn + srow) * K + scol;
    char* lA = (char*)As + wv * 1024;
    char* lB = (char*)Bs + wv * 1024;

    f32x4 acc[TM][4] = {};
    const int lane15 = ln & 15, quad = ln >> 4;
    const int koff = quad * 8;

    for (int k0 = 0; k0 < K; k0 += 32) {
        __syncthreads();
        gl_lds16(Ag + k0, lA);
        if (MT == 128) gl_lds16(Ag + (size_t)64 * K + k0, lA + 4096);
        gl_lds16(Bg + k0, lB);
        gl_lds16(Bg + (size_t)64 * K + k0, lB + 4096);
        __syncthreads();

        half8 aF[TM], bF[4];
#pragma unroll
        for (int i = 0; i < TM; ++i)
            aF[i] = *(const half8*)&As[(wm + i * 16 + lane15) * 32 + koff];
#pragma unroll
        for (int j = 0; j < 4; ++j)
            bF[j] = *(const half8*)&Bs[(wn + j * 16 + lane15) * 32 + koff];
#pragma unroll
        for (int i = 0; i < TM; ++i)
#pragma unroll
            for (int j = 0; j < 4; ++j)
                acc[i][j] = SW
                    ? __builtin_amdgcn_mfma_f32_16x16x32_f16(bF[j], aF[i], acc[i][j], 0, 0, 0)
                    : __builtin_amdgcn_mfma_f32_16x16x32_f16(aF[i], bF[j], acc[i][j], 0, 0, 0);
    }

    if (SW) {
        // D: m = lane15 (rows), n = quad*4 + r (regs) -> packed row-major stores
#pragma unroll
        for (int i = 0; i < TM; ++i) {
            const int gm = bm + wm + i * 16 + lane15;
#pragma unroll
            for (int j = 0; j < 4; ++j) {
                const int n0 = bn + wn + j * 16 + quad * 4;
                if (EPI == EPI_RES) {
                    f32x4 o = *(const f32x4*)&res[(size_t)gm * N + n0];
#pragma unroll
                    for (int r = 0; r < 4; ++r) o[r] += acc[i][j][r] + bias[n0 + r];
                    *(f32x4*)&Cf[(size_t)gm * N + n0] = o;
                } else {
                    half4 pk;
#pragma unroll
                    for (int r = 0; r < 4; ++r) {
                        float v = acc[i][j][r];
                        if (EPI == EPI_ATTN) {
                            int dist = gm - (n0 + r); if (dist < 0) dist = -dist;
                            v = v * alpha + bias[dist];
                        } else if (EPI == EPI_RELU) {
                            v = fmaxf(v + bias[n0 + r], 0.0f);
                        }
                        pk[r] = (half_t)v;
                    }
                    *(half4*)&Ch[(size_t)gm * N + n0] = pk;
                }
            }
        }
    } else {
        // original orientation: col = lane15 (n), row = quad*4 + r (m)
#pragma unroll
        for (int i = 0; i < TM; ++i) {
            const int m0 = bm + wm + i * 16 + quad * 4;
#pragma unroll
            for (int j = 0; j < 4; ++j) {
                const int gn = bn + wn + j * 16 + lane15;
                const int seg = gn >> 9, nn = gn & (DD - 1);
                if (seg == 2) {                  // V^T store, packed over rows (s)
                    half4 pk;
#pragma unroll
                    for (int r = 0; r < 4; ++r)
                        pk[r] = (half_t)(acc[i][j][r] + biasV[nn]);
                    const int b = m0 >> 11, s0 = m0 & (SS - 1);
                    *(half4*)&Cv[((size_t)b * DD + nn) * SS + s0] = pk;
                } else {
                    const float bs = (seg == 0) ? bias[nn] : biasK[nn];
                    half_t* dst = (seg == 0) ? Ch : Ck;
#pragma unroll
                    for (int r = 0; r < 4; ++r)
                        dst[(size_t)(m0 + r) * DD + nn] = (half_t)(acc[i][j][r] + bs);
                }
            }
        }
    }
}

// ---------------- in-place fp16 softmax over rows of [rows, SS] ----------------
__global__ __launch_bounds__(256) void softmax_kernel(half_t* __restrict__ p)
{
    __shared__ float sm[4];
    size_t row = blockIdx.x;
    half_t* r = p + row * SS;
    int t = threadIdx.x;
    half8 v8 = ((half8*)r)[t];
    float vals[8];
    float mx = -1e30f;
#pragma unroll
    for (int i = 0; i < 8; ++i) { vals[i] = (float)v8[i]; mx = fmaxf(mx, vals[i]); }
#pragma unroll
    for (int off = 32; off; off >>= 1) mx = fmaxf(mx, __shfl_down(mx, off));
    int lane = t & 63, w = t >> 6;
    if (lane == 0) sm[w] = mx;
    __syncthreads();
    mx = fmaxf(fmaxf(sm[0], sm[1]), fmaxf(sm[2], sm[3]));
    __syncthreads();
    float s = 0.f;
#pragma unroll
    for (int i = 0; i < 8; ++i) { vals[i] = __expf(vals[i] - mx); s += vals[i]; }
#pragma unroll
    for (int off = 32; off; off >>= 1) s += __shfl_down(s, off);
    if (lane == 0) sm[w] = s;
    __syncthreads();
    s = sm[0] + sm[1] + sm[2] + sm[3];
    float inv = 1.0f / s;
#pragma unroll
    for (int i = 0; i < 8; ++i) v8[i] = (half_t)(vals[i] * inv);
    ((half8*)r)[t] = v8;
}

// ---------------- out = x @ out_w^T + out_b  (ODIM=1) ----------------
__global__ __launch_bounds__(256) void out_kernel(
    const float* __restrict__ x, const float* __restrict__ ow,
    const float* __restrict__ ob, float* __restrict__ out)
{
    int row = blockIdx.x * 4 + (threadIdx.x >> 6);
    int lane = threadIdx.x & 63;
    const float* p = x + (size_t)row * DD;
    float s = 0.f;
#pragma unroll
    for (int k = 0; k < 8; ++k) s += p[lane + 64 * k] * ow[lane + 64 * k];
#pragma unroll
    for (int off = 32; off; off >>= 1) s += __shfl_down(s, off);
    if (lane == 0) out[row] = s + ob[0];
}

// ---------------- launch ----------------
extern "C" void kernel_launch(void* const* d_in, const int* in_sizes, int n_in,
                              void* d_out, int out_size, void* d_ws, size_t ws_size,
                              hipStream_t stream)
{
    (void)in_sizes; (void)n_in; (void)out_size; (void)ws_size;
    const float* z     = (const float*)d_in[0];
    const float* c     = (const float*)d_in[1];
    const float* enc_w = (const float*)d_in[2];
    const float* enc_b = (const float*)d_in[3];
    const float* beta  = (const float*)d_in[4];
    const float* wq    = (const float*)d_in[5];
    const float* bq    = (const float*)d_in[6];
    const float* wk    = (const float*)d_in[7];
    const float* bk    = (const float*)d_in[8];
    const float* wv    = (const float*)d_in[9];
    const float* bv    = (const float*)d_in[10];
    const float* ln1w  = (const float*)d_in[11];
    const float* ln1b  = (const float*)d_in[12];
    const float* ln2w  = (const float*)d_in[13];
    const float* ln2b  = (const float*)d_in[14];
    const float* ff1w  = (const float*)d_in[15];
    const float* ff1b  = (const float*)d_in[16];
    const float* ff2w  = (const float*)d_in[17];
    const float* ff2b  = (const float*)d_in[18];
    const float* ow    = (const float*)d_in[19];
    const float* ob    = (const float*)d_in[20];

    const size_t BSD = (size_t)BB * SS * DD;   // 8.39M
    const size_t BSS = (size_t)BB * SS * SS;   // 33.6M

    // Workspace: 190.4 MB total.
    char* p = (char*)d_ws;
    float*  x    = (float*)p;  p += BSD * 4;        // 33.55 MB
    half_t* xnh  = (half_t*)p; p += BSD * 2;        // 16.78 MB
    half_t* sch  = (half_t*)p; p += BSS * 2;        // 67.11 MB  scores/probs in-place
    char*   pool = p;          p += BSD * 2 * 4;    // 67.11 MB
    half_t* atth = (half_t*)pool;                   // dead before hh written
    half_t* qh   = (half_t*)(pool + BSD * 2);
    half_t* kh   = (half_t*)(pool + BSD * 4);
    half_t* vth  = (half_t*)(pool + BSD * 6);       // [B][D][S]
    half_t* hh   = (half_t*)pool;                   // aliases pool (BS x FFD)
    half_t* wqkv = (half_t*)p; p += (size_t)3 * DD * DD * 2;   // 1.57 MB
    half_t* f1h  = (half_t*)p; p += (size_t)FFD * DD * 2;      // 2.10 MB
    half_t* f2h  = (half_t*)p; p += (size_t)FFD * DD * 2;      // 2.10 MB
    float*  tbl  = (float*)p;                                  // 48 KB

    const float alpha = 0.044194173824159216f;      // 1/sqrt(512)
    const int BS = BB * SS;
    const long long sQ = (long long)SS * DD, sP = (long long)SS * SS,
                    sV = (long long)DD * SS;
    const int CONV_BLKS = (3 * DD * DD + 2 * FFD * DD) / 256;   // 11264

    bias_table_kernel<<<LL * SS / 256, 256, 0, stream>>>(beta, tbl);
    encode_kernel<<<BS * DD / 256, 256, 0, stream>>>(z, c, enc_w, enc_b, x);

    for (int l = 0; l < LL; ++l) {
        convert_layer_kernel<<<CONV_BLKS, 256, 0, stream>>>(
            wq + (size_t)l * DD * DD, wk + (size_t)l * DD * DD,
            wv + (size_t)l * DD * DD, ff1w + (size_t)l * FFD * DD,
            ff2w + (size_t)l * DD * FFD, wqkv, f1h, f2h);

        ln_kernel<<<BS, 256, 0, stream>>>(x, ln1w + l * DD, ln1b + l * DD, xnh);

        // fused QKV: one dispatch, 1536 blocks
        gemm_mfma<128, EPI_QKV, true><<<dim3(BS / 128, 12, 1), 256, 0, stream>>>(
            xnh, wqkv, bq + l * DD, nullptr, qh, DD, DD, 0, 0, 0, 0,
            bk + l * DD, bv + l * DD, kh, vth);

        // QK^T * alpha + cos-bias -> fp16 scores (full batch, 2048 blocks)
        gemm_mfma<128, EPI_ATTN, true><<<dim3(SS / 128, SS / 128, BB), 256, 0, stream>>>(
            qh, kh, tbl + l * SS, nullptr, sch, SS, DD, alpha, sQ, sQ, sP,
            nullptr, nullptr, nullptr, nullptr);

        softmax_kernel<<<BS, 256, 0, stream>>>(sch);

        // P @ V (64-row tiles -> 1024 blocks)
        gemm_mfma<64, EPI_NONE, true><<<dim3(SS / 64, DD / 128, BB), 256, 0, stream>>>(
            sch, vth, nullptr, nullptr, atth, DD, SS, 0, sP, sV, sQ,
            nullptr, nullptr, nullptr, nullptr);

        add_ln_ln_kernel<<<BS, 256, 0, stream>>>(x, atth, ln1w + l * DD, ln1b + l * DD,
                                                 ln2w + l * DD, ln2b + l * DD, xnh);

        // FFN
        gemm_mfma<128, EPI_RELU, true><<<dim3(BS / 128, FFD / 128, 1), 256, 0, stream>>>(
            xnh, f1h, ff1b + l * FFD, nullptr, hh, FFD, DD, 0, 0, 0, 0,
            nullptr, nullptr, nullptr, nullptr);
        gemm_mfma<64, EPI_RES, false><<<dim3(BS / 64, DD / 128, 1), 256, 0, stream>>>(
            hh, f2h, ff2b + l * DD, x, x, DD, FFD, 0, 0, 0, 0,
            nullptr, nullptr, nullptr, nullptr);
    }

    out_kernel<<<BS / 4, 256, 0, stream>>>(x, ow, ob, (float*)d_out);
}

// Round 5
// 2038.587 us; speedup vs baseline: 1.1757x; 1.1757x over previous
//
#include <hip/hip_runtime.h>
#include <math.h>

#define BB 8
#define SS 2048
#define DD 512
#define LL 6
#define FFD 2048   // 4*D

typedef _Float16 half_t;
typedef __attribute__((ext_vector_type(8))) _Float16 half8;
typedef __attribute__((ext_vector_type(4))) _Float16 half4;
typedef __attribute__((ext_vector_type(4))) float f32x4;

enum { EPI_NONE = 0, EPI_RELU = 2, EPI_RES = 3, EPI_ATTN = 4, EPI_QKV = 5, EPI_PV = 6 };

// ---------------- async global->LDS, 16B per lane ----------------
__device__ __forceinline__ void gl_lds16(const void* g, void* l) {
    __builtin_amdgcn_global_load_lds(
        (const __attribute__((address_space(1))) unsigned int*)g,
        (__attribute__((address_space(3))) unsigned int*)l,
        16, 0, 0);
}

__device__ __forceinline__ void blockReduce2(float& a, float& b, float* sm) {
#pragma unroll
    for (int off = 32; off; off >>= 1) {
        a += __shfl_down(a, off);
        b += __shfl_down(b, off);
    }
    int lane = threadIdx.x & 63;
    int w = threadIdx.x >> 6;
    if (lane == 0) { sm[w] = a; sm[4 + w] = b; }
    __syncthreads();
    a = sm[0] + sm[1] + sm[2] + sm[3];
    b = sm[4] + sm[5] + sm[6] + sm[7];
    __syncthreads();
}

// ---------------- encoder ----------------
__global__ __launch_bounds__(256) void encode_kernel(
    const float* __restrict__ z, const float* __restrict__ c,
    const float* __restrict__ enc_w, const float* __restrict__ enc_b,
    float* __restrict__ x)
{
    int idx = blockIdx.x * 256 + threadIdx.x;
    int d  = idx & (DD - 1);
    int bs = idx >> 9;
    int s  = bs & (SS - 1);
    float v = z[bs] * enc_w[2 * d] + c[bs] * enc_w[2 * d + 1] + enc_b[d];
    float div = expf(-(float)(d & ~1) * (9.210340371976184f / 512.0f));
    float ang = (float)s * div;
    v += (d & 1) ? cosf(ang) : sinf(ang);
    x[idx] = v;
}

// ------- per-layer weight conversion, one dispatch: [wq|wk|wv] + ff1 + ff2 -------
__global__ __launch_bounds__(256) void convert_layer_kernel(
    const float* __restrict__ wq, const float* __restrict__ wk,
    const float* __restrict__ wv, const float* __restrict__ f1,
    const float* __restrict__ f2, half_t* __restrict__ wqkv,
    half_t* __restrict__ f1h, half_t* __restrict__ f2h)
{
    const int NQ = DD * DD;                      // 262144
    int i = blockIdx.x * 256 + threadIdx.x;
    if (i < 3 * NQ) {
        int which = i >> 18, j = i & (NQ - 1);
        const float* s = (which == 0) ? wq : (which == 1) ? wk : wv;
        wqkv[i] = (half_t)s[j];
    } else {
        int k = i - 3 * NQ;
        if (k < FFD * DD) f1h[k] = (half_t)f1[k];
        else              f2h[k - FFD * DD] = (half_t)f2[k - FFD * DD];
    }
}

// ---------------- attention bias tables: tbl[l][dist] ----------------
__global__ __launch_bounds__(256) void bias_table_kernel(
    const float* __restrict__ beta, float* __restrict__ tbl)
{
    int i = blockIdx.x * 256 + threadIdx.x;   // L*2048
    int l = i >> 11, d = i & (SS - 1);
    tbl[i] = beta[2 * l] * cosf(0.2617993877991494f * d)
           + beta[2 * l + 1] * cosf(0.008726646259971648f * d);
}

// ---------------- LN: dst(half) = LN(src)*w + b ----------------
__global__ __launch_bounds__(256) void ln_kernel(
    const float* __restrict__ src, const float* __restrict__ w,
    const float* __restrict__ b, half_t* __restrict__ dst)
{
    __shared__ float sm[8];
    size_t row = blockIdx.x;
    const float* p = src + row * DD;
    int t = threadIdx.x;
    float v0 = p[t], v1 = p[t + 256];
    float s = v0 + v1, sq = v0 * v0 + v1 * v1;
    blockReduce2(s, sq, sm);
    float mean = s * (1.0f / DD);
    float var  = sq * (1.0f / DD) - mean * mean;
    float rs   = rsqrtf(var + 1e-5f);
    dst[row * DD + t]       = (half_t)((v0 - mean) * rs * w[t] + b[t]);
    dst[row * DD + t + 256] = (half_t)((v1 - mean) * rs * w[t + 256] + b[t + 256]);
}

// -------- fused: x = LN(x + att, w1,b1); xn(half) = LN(x, w2,b2) --------
__global__ __launch_bounds__(256) void add_ln_ln_kernel(
    float* __restrict__ x, const half_t* __restrict__ att,
    const float* __restrict__ w1, const float* __restrict__ b1,
    const float* __restrict__ w2, const float* __restrict__ b2,
    half_t* __restrict__ xn)
{
    __shared__ float sm[8];
    size_t row = blockIdx.x;
    int t = threadIdx.x;
    float v0 = x[row * DD + t] + (float)att[row * DD + t];
    float v1 = x[row * DD + t + 256] + (float)att[row * DD + t + 256];
    float s = v0 + v1, sq = v0 * v0 + v1 * v1;
    blockReduce2(s, sq, sm);
    float mean = s * (1.0f / DD);
    float var  = sq * (1.0f / DD) - mean * mean;
    float rs   = rsqrtf(var + 1e-5f);
    float y0 = (v0 - mean) * rs * w1[t] + b1[t];
    float y1 = (v1 - mean) * rs * w1[t + 256] + b1[t + 256];
    x[row * DD + t]       = y0;
    x[row * DD + t + 256] = y1;
    s = y0 + y1; sq = y0 * y0 + y1 * y1;
    blockReduce2(s, sq, sm);
    mean = s * (1.0f / DD);
    var  = sq * (1.0f / DD) - mean * mean;
    rs   = rsqrtf(var + 1e-5f);
    xn[row * DD + t]       = (half_t)((y0 - mean) * rs * w2[t] + b2[t]);
    xn[row * DD + t + 256] = (half_t)((y1 - mean) * rs * w2[t + 256] + b2[t + 256]);
}

// ---------------- MFMA fp16 NT GEMM, double-buffered pipelined K-loop ----------------
// C[m,n] = sum_k A[m,k]*W[n,k]. Tile MT x 128, BK=32, 256 thr = 4 waves.
// One barrier per K-iter: prefetch tile k+1 into the other LDS buffer before
// computing tile k; the barrier's implicit vmcnt(0) then waits on a load that
// has been in flight for a full compute iteration.
// EPI_ATTN: writes exp(min(v*alpha + tbl[|m-n|], 10)) -- lazy softmax numerator.
// EPI_PV  : v *= res[m] (res = per-row 1/sum, z-strided by SS).
// EPI_QKV : N-segments of 512 -> Q(+bias), K(+biasK), V^T(+biasV, [b][d][s]).
template<int MT, int EPI, bool OHALF>
__global__ __launch_bounds__(256) void gemm_mfma(
    const half_t* __restrict__ A, const half_t* __restrict__ W,
    const float* __restrict__ bias, const float* __restrict__ res,
    void* __restrict__ Cp, int N, int K, float alpha,
    long long sA, long long sW, long long sC,
    const float* __restrict__ biasK, const float* __restrict__ biasV,
    half_t* __restrict__ Ck, half_t* __restrict__ Cv)
{
    constexpr int TM = MT / 32;                  // mfma m-tiles per wave
    constexpr int ABUF = MT * 32;                // halfs per A buffer
    constexpr int BBUF = 128 * 32;
    __shared__ __align__(16) half_t As[2 * ABUF];
    __shared__ __align__(16) half_t Bs[2 * BBUF];

    const int z = blockIdx.z;
    A += (size_t)z * sA; W += (size_t)z * sW;
    if (EPI == EPI_PV) res += (size_t)z * SS;
    float*  Cf = (float*)Cp  + (size_t)z * sC;
    half_t* Ch = (half_t*)Cp + (size_t)z * sC;

    const int tid = threadIdx.x;
    const int wv = tid >> 6, ln = tid & 63;
    const int bm = blockIdx.x * MT, bn = blockIdx.y * 128;
    const int wm = (wv & 1) * (MT / 2), wn = (wv >> 1) * 64;

    const int srow = wv * 16 + (ln >> 2);        // 0..63
    const int scol = (ln & 3) * 8;
    const half_t* Ag = A + (size_t)(bm + srow) * K + scol;
    const half_t* Bg = W + (size_t)(bn + srow) * K + scol;

    f32x4 acc[TM][4] = {};
    const int lane15 = ln & 15, quad = ln >> 4;
    const int koff = quad * 8;
    const int nIter = K >> 5;

    // prologue: tile 0 -> buffer 0
    {
        char* a = (char*)As + wv * 1024;
        char* b = (char*)Bs + wv * 1024;
        gl_lds16(Ag, a);
        if (MT == 128) gl_lds16(Ag + (size_t)64 * K, a + 4096);
        gl_lds16(Bg, b);
        gl_lds16(Bg + (size_t)64 * K, b + 4096);
    }
    __syncthreads();    // drains prologue loads (compiler emits vmcnt(0))

    for (int it = 0; it < nIter; ++it) {
        const int cur = it & 1;
        if (it + 1 < nIter) {                    // prefetch tile it+1 -> other buf
            const int k1 = (it + 1) << 5;
            char* a = (char*)As + (cur ^ 1) * (ABUF * 2) + wv * 1024;
            char* b = (char*)Bs + (cur ^ 1) * (BBUF * 2) + wv * 1024;
            gl_lds16(Ag + k1, a);
            if (MT == 128) gl_lds16(Ag + (size_t)64 * K + k1, a + 4096);
            gl_lds16(Bg + k1, b);
            gl_lds16(Bg + (size_t)64 * K + k1, b + 4096);
        }

        const half_t* Ab = As + cur * ABUF;
        const half_t* Bb = Bs + cur * BBUF;
        half8 aF[TM], bF[4];
#pragma unroll
        for (int i = 0; i < TM; ++i)
            aF[i] = *(const half8*)&Ab[(wm + i * 16 + lane15) * 32 + koff];
#pragma unroll
        for (int j = 0; j < 4; ++j)
            bF[j] = *(const half8*)&Bb[(wn + j * 16 + lane15) * 32 + koff];
#pragma unroll
        for (int i = 0; i < TM; ++i)
#pragma unroll
            for (int j = 0; j < 4; ++j)
                acc[i][j] = __builtin_amdgcn_mfma_f32_16x16x32_f16(
                    aF[i], bF[j], acc[i][j], 0, 0, 0);

        __syncthreads();   // waits prefetch (1 iter in flight) + guards buf reuse
    }

    // epilogue; C/D layout: col = lane&15, row = quad*4 + r
#pragma unroll
    for (int i = 0; i < TM; ++i) {
        const int m0 = bm + wm + i * 16 + quad * 4;
#pragma unroll
        for (int j = 0; j < 4; ++j) {
            const int gn = bn + wn + j * 16 + lane15;
            if (EPI == EPI_QKV) {
                const int seg = gn >> 9, nn = gn & (DD - 1);
                if (seg == 2) {                  // V^T store, packed over rows (s)
                    half4 pk;
#pragma unroll
                    for (int r = 0; r < 4; ++r)
                        pk[r] = (half_t)(acc[i][j][r] + biasV[nn]);
                    const int b = m0 >> 11, s0 = m0 & (SS - 1);
                    *(half4*)&Cv[((size_t)b * DD + nn) * SS + s0] = pk;
                } else {
                    const float bs = (seg == 0) ? bias[nn] : biasK[nn];
                    half_t* dst = (seg == 0) ? Ch : Ck;
#pragma unroll
                    for (int r = 0; r < 4; ++r)
                        dst[(size_t)(m0 + r) * DD + nn] = (half_t)(acc[i][j][r] + bs);
                }
            } else {
#pragma unroll
                for (int r = 0; r < 4; ++r) {
                    const int gm = m0 + r;
                    float v = acc[i][j][r];
                    if (EPI == EPI_ATTN) {
                        int dist = gm - gn; if (dist < 0) dist = -dist;
                        v = __expf(fminf(v * alpha + bias[dist], 10.0f));
                    } else if (EPI == EPI_PV) {
                        v *= res[gm];
                    } else {
                        if (EPI == EPI_RELU) v = fmaxf(v + bias[gn], 0.0f);
                        if (EPI == EPI_RES)  v += bias[gn] + res[(size_t)gm * N + gn];
                    }
                    if (OHALF) Ch[(size_t)gm * N + gn] = (half_t)v;
                    else       Cf[(size_t)gm * N + gn] = v;
                }
            }
        }
    }
}

// ---------------- row sums of exp-scores -> reciprocal ----------------
__global__ __launch_bounds__(256) void rowsum_kernel(
    const half_t* __restrict__ sc, float* __restrict__ inv)
{
    int row = blockIdx.x * 4 + (threadIdx.x >> 6);
    int lane = threadIdx.x & 63;
    const half8* r = (const half8*)(sc + (size_t)row * SS);
    float s = 0.f;
#pragma unroll
    for (int k = 0; k < 4; ++k) {
        half8 v = r[lane + 64 * k];
#pragma unroll
        for (int i = 0; i < 8; ++i) s += (float)v[i];
    }
#pragma unroll
    for (int off = 32; off; off >>= 1) s += __shfl_down(s, off);
    if (lane == 0) inv[row] = 1.0f / s;
}

// ---------------- out = x @ out_w^T + out_b  (ODIM=1) ----------------
__global__ __launch_bounds__(256) void out_kernel(
    const float* __restrict__ x, const float* __restrict__ ow,
    const float* __restrict__ ob, float* __restrict__ out)
{
    int row = blockIdx.x * 4 + (threadIdx.x >> 6);
    int lane = threadIdx.x & 63;
    const float* p = x + (size_t)row * DD;
    float s = 0.f;
#pragma unroll
    for (int k = 0; k < 8; ++k) s += p[lane + 64 * k] * ow[lane + 64 * k];
#pragma unroll
    for (int off = 32; off; off >>= 1) s += __shfl_down(s, off);
    if (lane == 0) out[row] = s + ob[0];
}

// ---------------- launch ----------------
extern "C" void kernel_launch(void* const* d_in, const int* in_sizes, int n_in,
                              void* d_out, int out_size, void* d_ws, size_t ws_size,
                              hipStream_t stream)
{
    (void)in_sizes; (void)n_in; (void)out_size; (void)ws_size;
    const float* z     = (const float*)d_in[0];
    const float* c     = (const float*)d_in[1];
    const float* enc_w = (const float*)d_in[2];
    const float* enc_b = (const float*)d_in[3];
    const float* beta  = (const float*)d_in[4];
    const float* wq    = (const float*)d_in[5];
    const float* bq    = (const float*)d_in[6];
    const float* wk    = (const float*)d_in[7];
    const float* bk    = (const float*)d_in[8];
    const float* wv    = (const float*)d_in[9];
    const float* bv    = (const float*)d_in[10];
    const float* ln1w  = (const float*)d_in[11];
    const float* ln1b  = (const float*)d_in[12];
    const float* ln2w  = (const float*)d_in[13];
    const float* ln2b  = (const float*)d_in[14];
    const float* ff1w  = (const float*)d_in[15];
    const float* ff1b  = (const float*)d_in[16];
    const float* ff2w  = (const float*)d_in[17];
    const float* ff2b  = (const float*)d_in[18];
    const float* ow    = (const float*)d_in[19];
    const float* ob    = (const float*)d_in[20];

    const size_t BSD = (size_t)BB * SS * DD;   // 8.39M
    const size_t BSS = (size_t)BB * SS * SS;   // 33.6M

    // Workspace: ~190.5 MB total.
    char* p = (char*)d_ws;
    float*  x    = (float*)p;  p += BSD * 4;        // 33.55 MB
    half_t* xnh  = (half_t*)p; p += BSD * 2;        // 16.78 MB
    half_t* sch  = (half_t*)p; p += BSS * 2;        // 67.11 MB  exp-scores
    char*   pool = p;          p += BSD * 2 * 4;    // 67.11 MB
    half_t* atth = (half_t*)pool;                   // dead before hh written
    half_t* qh   = (half_t*)(pool + BSD * 2);
    half_t* kh   = (half_t*)(pool + BSD * 4);
    half_t* vth  = (half_t*)(pool + BSD * 6);       // [B][D][S]
    half_t* hh   = (half_t*)pool;                   // aliases pool (BS x FFD)
    half_t* wqkv = (half_t*)p; p += (size_t)3 * DD * DD * 2;   // 1.57 MB
    half_t* f1h  = (half_t*)p; p += (size_t)FFD * DD * 2;      // 2.10 MB
    half_t* f2h  = (half_t*)p; p += (size_t)FFD * DD * 2;      // 2.10 MB
    float*  tbl  = (float*)p;  p += (size_t)LL * SS * 4;       // 48 KB
    float*  sums = (float*)p;                                  // 64 KB

    const float alpha = 0.044194173824159216f;      // 1/sqrt(512)
    const int BS = BB * SS;
    const long long sQ = (long long)SS * DD, sP = (long long)SS * SS,
                    sV = (long long)DD * SS;
    const int CONV_BLKS = (3 * DD * DD + 2 * FFD * DD) / 256;   // 11264

    bias_table_kernel<<<LL * SS / 256, 256, 0, stream>>>(beta, tbl);
    encode_kernel<<<BS * DD / 256, 256, 0, stream>>>(z, c, enc_w, enc_b, x);

    for (int l = 0; l < LL; ++l) {
        convert_layer_kernel<<<CONV_BLKS, 256, 0, stream>>>(
            wq + (size_t)l * DD * DD, wk + (size_t)l * DD * DD,
            wv + (size_t)l * DD * DD, ff1w + (size_t)l * FFD * DD,
            ff2w + (size_t)l * DD * FFD, wqkv, f1h, f2h);

        ln_kernel<<<BS, 256, 0, stream>>>(x, ln1w + l * DD, ln1b + l * DD, xnh);

        // fused QKV: one dispatch, 1536 blocks
        gemm_mfma<128, EPI_QKV, true><<<dim3(BS / 128, 12, 1), 256, 0, stream>>>(
            xnh, wqkv, bq + l * DD, nullptr, qh, DD, DD, 0, 0, 0, 0,
            bk + l * DD, bv + l * DD, kh, vth);

        // QK^T -> exp(s*alpha + cos-bias) as fp16 (lazy-softmax numerator)
        gemm_mfma<128, EPI_ATTN, true><<<dim3(SS / 128, SS / 128, BB), 256, 0, stream>>>(
            qh, kh, tbl + l * SS, nullptr, sch, SS, DD, alpha, sQ, sQ, sP,
            nullptr, nullptr, nullptr, nullptr);

        rowsum_kernel<<<BS / 4, 256, 0, stream>>>(sch, sums);

        // P @ V with epilogue scale by 1/rowsum  (1024 blocks)
        gemm_mfma<64, EPI_PV, true><<<dim3(SS / 64, DD / 128, BB), 256, 0, stream>>>(
            sch, vth, nullptr, sums, atth, DD, SS, 0, sP, sV, sQ,
            nullptr, nullptr, nullptr, nullptr);

        add_ln_ln_kernel<<<BS, 256, 0, stream>>>(x, atth, ln1w + l * DD, ln1b + l * DD,
                                                 ln2w + l * DD, ln2b + l * DD, xnh);

        // FFN
        gemm_mfma<128, EPI_RELU, true><<<dim3(BS / 128, FFD / 128, 1), 256, 0, stream>>>(
            xnh, f1h, ff1b + l * FFD, nullptr, hh, FFD, DD, 0, 0, 0, 0,
            nullptr, nullptr, nullptr, nullptr);
        gemm_mfma<64, EPI_RES, false><<<dim3(BS / 64, DD / 128, 1), 256, 0, stream>>>(
            hh, f2h, ff2b + l * DD, x, x, DD, FFD, 0, 0, 0, 0,
            nullptr, nullptr, nullptr, nullptr);
    }

    out_kernel<<<BS / 4, 256, 0, stream>>>(x, ow, ob, (float*)d_out);
}

// Round 6
// 1975.864 us; speedup vs baseline: 1.2130x; 1.0317x over previous
//
#include <hip/hip_runtime.h>
#include <math.h>

#define BB 8
#define SS 2048
#define DD 512
#define LL 6
#define FFD 2048   // 4*D

typedef _Float16 half_t;
typedef __attribute__((ext_vector_type(8))) _Float16 half8;
typedef __attribute__((ext_vector_type(4))) _Float16 half4;
typedef __attribute__((ext_vector_type(4))) float f32x4;

enum { EPI_NONE = 0, EPI_RELU = 2, EPI_RES = 3, EPI_ATTN = 4, EPI_QKV = 5, EPI_PV = 6 };

// ---------------- async global->LDS, 16B per lane ----------------
__device__ __forceinline__ void gl_lds16(const void* g, void* l) {
    __builtin_amdgcn_global_load_lds(
        (const __attribute__((address_space(1))) unsigned int*)g,
        (__attribute__((address_space(3))) unsigned int*)l,
        16, 0, 0);
}

__device__ __forceinline__ void blockReduce2(float& a, float& b, float* sm) {
#pragma unroll
    for (int off = 32; off; off >>= 1) {
        a += __shfl_down(a, off);
        b += __shfl_down(b, off);
    }
    int lane = threadIdx.x & 63;
    int w = threadIdx.x >> 6;
    if (lane == 0) { sm[w] = a; sm[4 + w] = b; }
    __syncthreads();
    a = sm[0] + sm[1] + sm[2] + sm[3];
    b = sm[4] + sm[5] + sm[6] + sm[7];
    __syncthreads();
}

// ---------------- encoder ----------------
__global__ __launch_bounds__(256) void encode_kernel(
    const float* __restrict__ z, const float* __restrict__ c,
    const float* __restrict__ enc_w, const float* __restrict__ enc_b,
    float* __restrict__ x)
{
    int idx = blockIdx.x * 256 + threadIdx.x;
    int d  = idx & (DD - 1);
    int bs = idx >> 9;
    int s  = bs & (SS - 1);
    float v = z[bs] * enc_w[2 * d] + c[bs] * enc_w[2 * d + 1] + enc_b[d];
    float div = expf(-(float)(d & ~1) * (9.210340371976184f / 512.0f));
    float ang = (float)s * div;
    v += (d & 1) ? cosf(ang) : sinf(ang);
    x[idx] = v;
}

// ------- per-layer weight conversion, one dispatch: [wq|wk|wv] + ff1 + ff2 -------
__global__ __launch_bounds__(256) void convert_layer_kernel(
    const float* __restrict__ wq, const float* __restrict__ wk,
    const float* __restrict__ wv, const float* __restrict__ f1,
    const float* __restrict__ f2, half_t* __restrict__ wqkv,
    half_t* __restrict__ f1h, half_t* __restrict__ f2h)
{
    const int NQ = DD * DD;                      // 262144
    int i = blockIdx.x * 256 + threadIdx.x;
    if (i < 3 * NQ) {
        int which = i >> 18, j = i & (NQ - 1);
        const float* s = (which == 0) ? wq : (which == 1) ? wk : wv;
        wqkv[i] = (half_t)s[j];
    } else {
        int k = i - 3 * NQ;
        if (k < FFD * DD) f1h[k] = (half_t)f1[k];
        else              f2h[k - FFD * DD] = (half_t)f2[k - FFD * DD];
    }
}

// ---------------- attention bias tables: tbl[l][dist] ----------------
__global__ __launch_bounds__(256) void bias_table_kernel(
    const float* __restrict__ beta, float* __restrict__ tbl)
{
    int i = blockIdx.x * 256 + threadIdx.x;   // L*2048
    int l = i >> 11, d = i & (SS - 1);
    tbl[i] = beta[2 * l] * cosf(0.2617993877991494f * d)
           + beta[2 * l + 1] * cosf(0.008726646259971648f * d);
}

// ---------------- LN: dst(half) = LN(src)*w + b ----------------
__global__ __launch_bounds__(256) void ln_kernel(
    const float* __restrict__ src, const float* __restrict__ w,
    const float* __restrict__ b, half_t* __restrict__ dst)
{
    __shared__ float sm[8];
    size_t row = blockIdx.x;
    const float* p = src + row * DD;
    int t = threadIdx.x;
    float v0 = p[t], v1 = p[t + 256];
    float s = v0 + v1, sq = v0 * v0 + v1 * v1;
    blockReduce2(s, sq, sm);
    float mean = s * (1.0f / DD);
    float var  = sq * (1.0f / DD) - mean * mean;
    float rs   = rsqrtf(var + 1e-5f);
    dst[row * DD + t]       = (half_t)((v0 - mean) * rs * w[t] + b[t]);
    dst[row * DD + t + 256] = (half_t)((v1 - mean) * rs * w[t + 256] + b[t + 256]);
}

// -------- fused: x = LN(x + att, w1,b1); xn(half) = LN(x, w2,b2) --------
__global__ __launch_bounds__(256) void add_ln_ln_kernel(
    float* __restrict__ x, const half_t* __restrict__ att,
    const float* __restrict__ w1, const float* __restrict__ b1,
    const float* __restrict__ w2, const float* __restrict__ b2,
    half_t* __restrict__ xn)
{
    __shared__ float sm[8];
    size_t row = blockIdx.x;
    int t = threadIdx.x;
    float v0 = x[row * DD + t] + (float)att[row * DD + t];
    float v1 = x[row * DD + t + 256] + (float)att[row * DD + t + 256];
    float s = v0 + v1, sq = v0 * v0 + v1 * v1;
    blockReduce2(s, sq, sm);
    float mean = s * (1.0f / DD);
    float var  = sq * (1.0f / DD) - mean * mean;
    float rs   = rsqrtf(var + 1e-5f);
    float y0 = (v0 - mean) * rs * w1[t] + b1[t];
    float y1 = (v1 - mean) * rs * w1[t + 256] + b1[t + 256];
    x[row * DD + t]       = y0;
    x[row * DD + t + 256] = y1;
    s = y0 + y1; sq = y0 * y0 + y1 * y1;
    blockReduce2(s, sq, sm);
    mean = s * (1.0f / DD);
    var  = sq * (1.0f / DD) - mean * mean;
    rs   = rsqrtf(var + 1e-5f);
    xn[row * DD + t]       = (half_t)((y0 - mean) * rs * w2[t] + b2[t]);
    xn[row * DD + t + 256] = (half_t)((y1 - mean) * rs * w2[t + 256] + b2[t + 256]);
}

// ---------------- MFMA fp16 NT GEMM, double-buffered pipelined K-loop ----------------
// C[m,n] = sum_k A[m,k]*W[n,k]. Tile MT x 128, BK=32, 256 thr = 4 waves.
// EPI_ATTN: writes exp(min(v*alpha + tbl[|m-n|], 10)) -- lazy softmax numerator.
// EPI_PV  : accumulates row-sums of A (= exp-scores) during the K-loop and
//           scales by the reciprocal in the epilogue (softmax denominator).
// EPI_QKV : N-segments of 512 -> Q(+bias), K(+biasK), V^T(+biasV, [b][d][s]).
// SWZ==1  : 1-D grid 2048 decoded so the 16 x-blocks of one (y,z) strip share
//           dispatch_id%8 (same XCD) -> B-strip stays in one L2.
template<int MT, int EPI, bool OHALF, int SWZ = 0>
__global__ __launch_bounds__(256) void gemm_mfma(
    const half_t* __restrict__ A, const half_t* __restrict__ W,
    const float* __restrict__ bias, const float* __restrict__ res,
    void* __restrict__ Cp, int N, int K, float alpha,
    long long sA, long long sW, long long sC,
    const float* __restrict__ biasK, const float* __restrict__ biasV,
    half_t* __restrict__ Ck, half_t* __restrict__ Cv)
{
    constexpr int TM = MT / 32;                  // mfma m-tiles per wave
    constexpr int ABUF = MT * 32;                // halfs per A buffer
    constexpr int BBUF = 128 * 32;
    __shared__ __align__(16) half_t As[2 * ABUF];
    __shared__ __align__(16) half_t Bs[2 * BBUF];

    int bxi, byi, bzi;
    if (SWZ == 1) {                              // 16 x 16 x 8 strip swizzle
        const int id = blockIdx.x;
        const int cc = id & 7, rr = id >> 3;
        bxi = rr & 15;
        const int ss = cc + 8 * (rr >> 4);
        byi = ss & 15; bzi = ss >> 4;
    } else { bxi = blockIdx.x; byi = blockIdx.y; bzi = blockIdx.z; }

    const int z = bzi;
    A += (size_t)z * sA; W += (size_t)z * sW;
    float*  Cf = (float*)Cp  + (size_t)z * sC;
    half_t* Ch = (half_t*)Cp + (size_t)z * sC;

    const int tid = threadIdx.x;
    const int wv = tid >> 6, ln = tid & 63;
    const int bm = bxi * MT, bn = byi * 128;
    const int wm = (wv & 1) * (MT / 2), wn = (wv >> 1) * 64;

    const int srow = wv * 16 + (ln >> 2);        // 0..63
    const int scol = (ln & 3) * 8;
    const half_t* Ag = A + (size_t)(bm + srow) * K + scol;
    const half_t* Bg = W + (size_t)(bn + srow) * K + scol;

    f32x4 acc[TM][4] = {};
    float rs[TM];
#pragma unroll
    for (int i = 0; i < TM; ++i) rs[i] = 0.f;

    const int lane15 = ln & 15, quad = ln >> 4;
    const int koff = quad * 8;
    const int nIter = K >> 5;

    // prologue: tile 0 -> buffer 0
    {
        char* a = (char*)As + wv * 1024;
        char* b = (char*)Bs + wv * 1024;
        gl_lds16(Ag, a);
        if (MT == 128) gl_lds16(Ag + (size_t)64 * K, a + 4096);
        gl_lds16(Bg, b);
        gl_lds16(Bg + (size_t)64 * K, b + 4096);
    }
    __syncthreads();

    for (int it = 0; it < nIter; ++it) {
        const int cur = it & 1;
        if (it + 1 < nIter) {                    // prefetch tile it+1 -> other buf
            const int k1 = (it + 1) << 5;
            char* a = (char*)As + (cur ^ 1) * (ABUF * 2) + wv * 1024;
            char* b = (char*)Bs + (cur ^ 1) * (BBUF * 2) + wv * 1024;
            gl_lds16(Ag + k1, a);
            if (MT == 128) gl_lds16(Ag + (size_t)64 * K + k1, a + 4096);
            gl_lds16(Bg + k1, b);
            gl_lds16(Bg + (size_t)64 * K + k1, b + 4096);
        }

        const half_t* Ab = As + cur * ABUF;
        const half_t* Bb = Bs + cur * BBUF;
        half8 aF[TM], bF[4];
#pragma unroll
        for (int i = 0; i < TM; ++i)
            aF[i] = *(const half8*)&Ab[(wm + i * 16 + lane15) * 32 + koff];
#pragma unroll
        for (int j = 0; j < 4; ++j)
            bF[j] = *(const half8*)&Bb[(wn + j * 16 + lane15) * 32 + koff];

        if (EPI == EPI_PV) {                     // inline softmax denominator
#pragma unroll
            for (int i = 0; i < TM; ++i)
#pragma unroll
                for (int e = 0; e < 8; ++e) rs[i] += (float)aF[i][e];
        }

#pragma unroll
        for (int i = 0; i < TM; ++i)
#pragma unroll
            for (int j = 0; j < 4; ++j)
                acc[i][j] = __builtin_amdgcn_mfma_f32_16x16x32_f16(
                    aF[i], bF[j], acc[i][j], 0, 0, 0);

        __syncthreads();
    }

    float inv[TM][4];
    if (EPI == EPI_PV) {
#pragma unroll
        for (int i = 0; i < TM; ++i) {
            rs[i] += __shfl_xor(rs[i], 16);      // reduce across quads
            rs[i] += __shfl_xor(rs[i], 32);
            rs[i] = 1.0f / rs[i];                // lane15 indexes the row
#pragma unroll
            for (int r = 0; r < 4; ++r)          // move to C-layout rows
                inv[i][r] = __shfl(rs[i], quad * 4 + r);
        }
    }

    // epilogue; C/D layout: col = lane&15, row = quad*4 + r
#pragma unroll
    for (int i = 0; i < TM; ++i) {
        const int m0 = bm + wm + i * 16 + quad * 4;
#pragma unroll
        for (int j = 0; j < 4; ++j) {
            const int gn = bn + wn + j * 16 + lane15;
            if (EPI == EPI_QKV) {
                const int seg = gn >> 9, nn = gn & (DD - 1);
                if (seg == 2) {                  // V^T store, packed over rows (s)
                    half4 pk;
#pragma unroll
                    for (int r = 0; r < 4; ++r)
                        pk[r] = (half_t)(acc[i][j][r] + biasV[nn]);
                    const int b = m0 >> 11, s0 = m0 & (SS - 1);
                    *(half4*)&Cv[((size_t)b * DD + nn) * SS + s0] = pk;
                } else {
                    const float bs = (seg == 0) ? bias[nn] : biasK[nn];
                    half_t* dst = (seg == 0) ? Ch : Ck;
#pragma unroll
                    for (int r = 0; r < 4; ++r)
                        dst[(size_t)(m0 + r) * DD + nn] = (half_t)(acc[i][j][r] + bs);
                }
            } else {
#pragma unroll
                for (int r = 0; r < 4; ++r) {
                    const int gm = m0 + r;
                    float v = acc[i][j][r];
                    if (EPI == EPI_ATTN) {
                        int dist = gm - gn; if (dist < 0) dist = -dist;
                        v = __expf(fminf(v * alpha + bias[dist], 10.0f));
                    } else if (EPI == EPI_PV) {
                        v *= inv[i][r];
                    } else {
                        if (EPI == EPI_RELU) v = fmaxf(v + bias[gn], 0.0f);
                        if (EPI == EPI_RES)  v += bias[gn] + res[(size_t)gm * N + gn];
                    }
                    if (OHALF) Ch[(size_t)gm * N + gn] = (half_t)v;
                    else       Cf[(size_t)gm * N + gn] = v;
                }
            }
        }
    }
}

// ---------------- out = x @ out_w^T + out_b  (ODIM=1) ----------------
__global__ __launch_bounds__(256) void out_kernel(
    const float* __restrict__ x, const float* __restrict__ ow,
    const float* __restrict__ ob, float* __restrict__ out)
{
    int row = blockIdx.x * 4 + (threadIdx.x >> 6);
    int lane = threadIdx.x & 63;
    const float* p = x + (size_t)row * DD;
    float s = 0.f;
#pragma unroll
    for (int k = 0; k < 8; ++k) s += p[lane + 64 * k] * ow[lane + 64 * k];
#pragma unroll
    for (int off = 32; off; off >>= 1) s += __shfl_down(s, off);
    if (lane == 0) out[row] = s + ob[0];
}

// ---------------- launch ----------------
extern "C" void kernel_launch(void* const* d_in, const int* in_sizes, int n_in,
                              void* d_out, int out_size, void* d_ws, size_t ws_size,
                              hipStream_t stream)
{
    (void)in_sizes; (void)n_in; (void)out_size; (void)ws_size;
    const float* z     = (const float*)d_in[0];
    const float* c     = (const float*)d_in[1];
    const float* enc_w = (const float*)d_in[2];
    const float* enc_b = (const float*)d_in[3];
    const float* beta  = (const float*)d_in[4];
    const float* wq    = (const float*)d_in[5];
    const float* bq    = (const float*)d_in[6];
    const float* wk    = (const float*)d_in[7];
    const float* bk    = (const float*)d_in[8];
    const float* wv    = (const float*)d_in[9];
    const float* bv    = (const float*)d_in[10];
    const float* ln1w  = (const float*)d_in[11];
    const float* ln1b  = (const float*)d_in[12];
    const float* ln2w  = (const float*)d_in[13];
    const float* ln2b  = (const float*)d_in[14];
    const float* ff1w  = (const float*)d_in[15];
    const float* ff1b  = (const float*)d_in[16];
    const float* ff2w  = (const float*)d_in[17];
    const float* ff2b  = (const float*)d_in[18];
    const float* ow    = (const float*)d_in[19];
    const float* ob    = (const float*)d_in[20];

    const size_t BSD = (size_t)BB * SS * DD;   // 8.39M
    const size_t BSS = (size_t)BB * SS * SS;   // 33.6M

    // Workspace: ~190.5 MB total.
    char* p = (char*)d_ws;
    float*  x    = (float*)p;  p += BSD * 4;        // 33.55 MB
    half_t* xnh  = (half_t*)p; p += BSD * 2;        // 16.78 MB
    half_t* sch  = (half_t*)p; p += BSS * 2;        // 67.11 MB  exp-scores
    char*   pool = p;          p += BSD * 2 * 4;    // 67.11 MB
    half_t* atth = (half_t*)pool;                   // dead before hh written
    half_t* qh   = (half_t*)(pool + BSD * 2);
    half_t* kh   = (half_t*)(pool + BSD * 4);
    half_t* vth  = (half_t*)(pool + BSD * 6);       // [B][D][S]
    half_t* hh   = (half_t*)pool;                   // aliases pool (BS x FFD)
    half_t* wqkv = (half_t*)p; p += (size_t)3 * DD * DD * 2;   // 1.57 MB
    half_t* f1h  = (half_t*)p; p += (size_t)FFD * DD * 2;      // 2.10 MB
    half_t* f2h  = (half_t*)p; p += (size_t)FFD * DD * 2;      // 2.10 MB
    float*  tbl  = (float*)p;                                  // 48 KB

    const float alpha = 0.044194173824159216f;      // 1/sqrt(512)
    const int BS = BB * SS;
    const long long sQ = (long long)SS * DD, sP = (long long)SS * SS,
                    sV = (long long)DD * SS;
    const int CONV_BLKS = (3 * DD * DD + 2 * FFD * DD) / 256;   // 11264

    bias_table_kernel<<<LL * SS / 256, 256, 0, stream>>>(beta, tbl);
    encode_kernel<<<BS * DD / 256, 256, 0, stream>>>(z, c, enc_w, enc_b, x);

    for (int l = 0; l < LL; ++l) {
        convert_layer_kernel<<<CONV_BLKS, 256, 0, stream>>>(
            wq + (size_t)l * DD * DD, wk + (size_t)l * DD * DD,
            wv + (size_t)l * DD * DD, ff1w + (size_t)l * FFD * DD,
            ff2w + (size_t)l * DD * FFD, wqkv, f1h, f2h);

        ln_kernel<<<BS, 256, 0, stream>>>(x, ln1w + l * DD, ln1b + l * DD, xnh);

        // fused QKV: one dispatch, 1536 blocks
        gemm_mfma<128, EPI_QKV, true><<<dim3(BS / 128, 12, 1), 256, 0, stream>>>(
            xnh, wqkv, bq + l * DD, nullptr, qh, DD, DD, 0, 0, 0, 0,
            bk + l * DD, bv + l * DD, kh, vth);

        // QK^T -> exp(s*alpha + cos-bias) fp16, XCD-swizzled 1-D grid
        gemm_mfma<128, EPI_ATTN, true, 1><<<dim3(2048, 1, 1), 256, 0, stream>>>(
            qh, kh, tbl + l * SS, nullptr, sch, SS, DD, alpha, sQ, sQ, sP,
            nullptr, nullptr, nullptr, nullptr);

        // P @ V with inline denominator + epilogue scale (1024 blocks)
        gemm_mfma<64, EPI_PV, true><<<dim3(SS / 64, DD / 128, BB), 256, 0, stream>>>(
            sch, vth, nullptr, nullptr, atth, DD, SS, 0, sP, sV, sQ,
            nullptr, nullptr, nullptr, nullptr);

        add_ln_ln_kernel<<<BS, 256, 0, stream>>>(x, atth, ln1w + l * DD, ln1b + l * DD,
                                                 ln2w + l * DD, ln2b + l * DD, xnh);

        // FFN
        gemm_mfma<128, EPI_RELU, true><<<dim3(BS / 128, FFD / 128, 1), 256, 0, stream>>>(
            xnh, f1h, ff1b + l * FFD, nullptr, hh, FFD, DD, 0, 0, 0, 0,
            nullptr, nullptr, nullptr, nullptr);
        gemm_mfma<64, EPI_RES, false><<<dim3(BS / 64, DD / 128, 1), 256, 0, stream>>>(
            hh, f2h, ff2b + l * DD, x, x, DD, FFD, 0, 0, 0, 0,
            nullptr, nullptr, nullptr, nullptr);
    }

    out_kernel<<<BS / 4, 256, 0, stream>>>(x, ow, ob, (float*)d_out);
}